// Round 1
// baseline (441.247 us; speedup 1.0000x reference)
//
#include <hip/hip_runtime.h>

// Problem: B=4, T=2048, C=768, H=12, D=64.  qkv = x@w_qkv^T, rope(q,k),
// causal softmax(q k^T / 8) v, out = y@w_o^T.  All interface fp32; internal bf16.
#define B_  4
#define T_  2048
#define C_  768
#define H_  12
#define D_  64
#define NQ_ 2304

typedef unsigned short u16;
typedef unsigned int   u32;
typedef __bf16 bf16;
typedef __bf16 bf16x8 __attribute__((ext_vector_type(8)));
typedef float  f32x4  __attribute__((ext_vector_type(4)));
typedef __attribute__((address_space(1))) void* gas_t;
typedef __attribute__((address_space(3))) void* las_t;

static __device__ __forceinline__ u16 f2bf(float f) {
  u32 u = __builtin_bit_cast(u32, f);
  u += 0x7FFFu + ((u >> 16) & 1u);          // RNE
  return (u16)(u >> 16);
}
static __device__ __forceinline__ float bf2f(u16 h) {
  u32 u = ((u32)h) << 16;
  return __builtin_bit_cast(float, u);
}

// ---------------- fp32 -> bf16 convert (vectorized) ----------------
__global__ __launch_bounds__(256) void k_cvt(const float* __restrict__ in,
                                             u16* __restrict__ out) {
  const int i = blockIdx.x * 256 + threadIdx.x;
  const float4 v = ((const float4*)in)[i];
  ushort4 o;
  o.x = f2bf(v.x); o.y = f2bf(v.y); o.z = f2bf(v.z); o.w = f2bf(v.w);
  ((ushort4*)out)[i] = o;
}

// ---------------- GEMM: C[m,n] = sum_k A[m,k]*Bt[n,k]  (bf16 in, bf16/f32 out)
// 128x128 tile, BK=32, 4 waves (2x2 of 64x64), 16x16x32 MFMA. m97-structure.
template<int OUTF32>
__global__ __launch_bounds__(256) void k_gemm_bt(const u16* __restrict__ A,
                                                 const u16* __restrict__ Bt,
                                                 void* __restrict__ Cout,
                                                 int M, int N, int K) {
  __shared__ u16 lA[128 * 32];
  __shared__ u16 lB[128 * 32];
  const int tid = threadIdx.x;
  const int l = tid & 63, w = tid >> 6;
  const int lo = l & 15, hi = l >> 4;
  const int wr = w >> 1, wc = w & 1;
  const int m0 = blockIdx.y * 128, n0 = blockIdx.x * 128;

  f32x4 acc[4][4] = {};
  for (int k0 = 0; k0 < K; k0 += 32) {
#pragma unroll
    for (int r = 0; r < 2; ++r) {
      const int c = tid + 256 * r;
      const int row = c >> 2, cb = (c & 3) * 8;
      __builtin_amdgcn_global_load_lds((gas_t)(u16*)(A + (size_t)(m0 + row) * K + k0 + cb),
                                       (las_t)(lA + c * 8), 16, 0, 0);
      __builtin_amdgcn_global_load_lds((gas_t)(u16*)(Bt + (size_t)(n0 + row) * K + k0 + cb),
                                       (las_t)(lB + c * 8), 16, 0, 0);
    }
    __syncthreads();
    bf16x8 af[4], bfr[4];
#pragma unroll
    for (int i = 0; i < 4; ++i)
      af[i] = *(const bf16x8*)(lA + (wr * 64 + i * 16 + lo) * 32 + hi * 8);
#pragma unroll
    for (int j = 0; j < 4; ++j)
      bfr[j] = *(const bf16x8*)(lB + (wc * 64 + j * 16 + lo) * 32 + hi * 8);
#pragma unroll
    for (int i = 0; i < 4; ++i)
#pragma unroll
      for (int j = 0; j < 4; ++j)
        acc[i][j] = __builtin_amdgcn_mfma_f32_16x16x32_bf16(af[i], bfr[j], acc[i][j], 0, 0, 0);
    __syncthreads();
  }
  const int crow = m0 + wr * 64, ccol = n0 + wc * 64;
  if (OUTF32) {
    float* Cp = (float*)Cout;
#pragma unroll
    for (int i = 0; i < 4; ++i)
#pragma unroll
      for (int j = 0; j < 4; ++j)
#pragma unroll
        for (int r = 0; r < 4; ++r)
          Cp[(size_t)(crow + i * 16 + hi * 4 + r) * N + ccol + j * 16 + lo] = acc[i][j][r];
  } else {
    u16* Cp = (u16*)Cout;
#pragma unroll
    for (int i = 0; i < 4; ++i)
#pragma unroll
      for (int j = 0; j < 4; ++j)
#pragma unroll
        for (int r = 0; r < 4; ++r)
          Cp[(size_t)(crow + i * 16 + hi * 4 + r) * N + ccol + j * 16 + lo] = f2bf(acc[i][j][r]);
  }
}

// ---------------- RoPE on q,k + relayout to (b,h,t,d); fold 1/sqrt(D) into q
__global__ __launch_bounds__(256) void k_rope(const u16* __restrict__ qkv,
                                              const float* __restrict__ rope,
                                              u16* __restrict__ qo, u16* __restrict__ ko) {
  const int p = blockIdx.x * 256 + threadIdx.x;   // ((b*T+t)*H + h)*32 + i
  const int i = p & 31;
  const int ph = p >> 5;
  const int h = ph % H_;
  const int bt = ph / H_;
  const int t = bt & (T_ - 1);
  const int b = bt >> 11;
  const size_t qrow = (size_t)bt * NQ_ + h * D_ + 2 * i;
  const ushort2 qp = *(const ushort2*)(qkv + qrow);
  const ushort2 kp = *(const ushort2*)(qkv + qrow + C_);
  const float2 cs = *(const float2*)(rope + ((size_t)t * 32 + i) * 2);
  const float q0 = bf2f(qp.x), q1 = bf2f(qp.y);
  const float k0 = bf2f(kp.x), k1 = bf2f(kp.y);
  const float sc = 0.125f;   // 1/sqrt(64)
  const float rq0 = (q0 * cs.x - q1 * cs.y) * sc;
  const float rq1 = (q0 * cs.y + q1 * cs.x) * sc;
  const float rk0 = k0 * cs.x - k1 * cs.y;
  const float rk1 = k0 * cs.y + k1 * cs.x;
  const size_t oo = (((size_t)(b * H_ + h) * T_) + t) * D_ + 2 * i;
  *(ushort2*)(qo + oo) = make_ushort2(f2bf(rq0), f2bf(rq1));
  *(ushort2*)(ko + oo) = make_ushort2(f2bf(rk0), f2bf(rk1));
}

// ---------------- V transpose: qkv v-slice -> Vt (b,h,d,t) via LDS tile
__global__ __launch_bounds__(256) void k_vtrans(const u16* __restrict__ qkv,
                                                u16* __restrict__ vt) {
  __shared__ u16 lds[64][68];
  const int bid = blockIdx.x;
  const int ttile = bid & 31, bh = bid >> 5;
  const int b = bh / H_, h = bh % H_;
  const int tid = threadIdx.x;
  const int tl = tid >> 2, doff = (tid & 3) * 16;
  const u16* src = qkv + (size_t)(b * T_ + ttile * 64 + tl) * NQ_ + 2 * C_ + h * D_ + doff;
  const uint4 v0 = *(const uint4*)(src);
  const uint4 v1 = *(const uint4*)(src + 8);
  *(uint2*)&lds[tl][doff + 0]  = make_uint2(v0.x, v0.y);
  *(uint2*)&lds[tl][doff + 4]  = make_uint2(v0.z, v0.w);
  *(uint2*)&lds[tl][doff + 8]  = make_uint2(v1.x, v1.y);
  *(uint2*)&lds[tl][doff + 12] = make_uint2(v1.z, v1.w);
  __syncthreads();
  const int d = tl, toff = doff;
  uint4 o0, o1;
#define PK(j) ((u32)lds[toff + (j)][d] | ((u32)lds[toff + (j) + 1][d] << 16))
  o0.x = PK(0);  o0.y = PK(2);  o0.z = PK(4);  o0.w = PK(6);
  o1.x = PK(8);  o1.y = PK(10); o1.z = PK(12); o1.w = PK(14);
#undef PK
  u16* dst = vt + ((size_t)bh * D_ + d) * T_ + ttile * 64 + toff;
  *(uint4*)(dst) = o0;
  *(uint4*)(dst + 8) = o1;
}

// ---------------- flash attention: wave = 16 q rows, KV tile = 32, causal
__global__ __launch_bounds__(256) void k_attn(const u16* __restrict__ qb,
                                              const u16* __restrict__ kb,
                                              const u16* __restrict__ vtb,
                                              u16* __restrict__ yb) {
  __shared__ u16 pbuf[4][16 * 32];
  const int tid = threadIdx.x;
  const int w = tid >> 6, l = tid & 63;
  const int lo = l & 15, hi = l >> 4;
  const int h = blockIdx.y, b = blockIdx.z;
  const int bh = b * H_ + h;
  const u16* Q  = qb  + (size_t)bh * T_ * D_;
  const u16* K  = kb  + (size_t)bh * T_ * D_;
  const u16* Vt = vtb + (size_t)bh * D_ * T_;
  const int q0w = blockIdx.x * 64 + w * 16;
  const bf16x8 qf0 = *(const bf16x8*)(Q + (q0w + lo) * D_ + hi * 8);
  const bf16x8 qf1 = *(const bf16x8*)(Q + (q0w + lo) * D_ + 32 + hi * 8);
  float mrow[4] = {-1e30f, -1e30f, -1e30f, -1e30f};
  float lrow[4] = {0.f, 0.f, 0.f, 0.f};
  f32x4 o[4] = {};
  u16* pb = &pbuf[w][0];
  const int ntiles = (q0w + 15) / 32 + 1;
  for (int ti = 0; ti < ntiles; ++ti) {
    const int j0 = ti * 32;
    f32x4 s0 = {0.f, 0.f, 0.f, 0.f}, s1 = {0.f, 0.f, 0.f, 0.f};
    {
      const bf16x8 k00 = *(const bf16x8*)(K + (j0 + lo) * D_ + hi * 8);
      const bf16x8 k01 = *(const bf16x8*)(K + (j0 + lo) * D_ + 32 + hi * 8);
      s0 = __builtin_amdgcn_mfma_f32_16x16x32_bf16(qf0, k00, s0, 0, 0, 0);
      s0 = __builtin_amdgcn_mfma_f32_16x16x32_bf16(qf1, k01, s0, 0, 0, 0);
      const bf16x8 k10 = *(const bf16x8*)(K + (j0 + 16 + lo) * D_ + hi * 8);
      const bf16x8 k11 = *(const bf16x8*)(K + (j0 + 16 + lo) * D_ + 32 + hi * 8);
      s1 = __builtin_amdgcn_mfma_f32_16x16x32_bf16(qf0, k10, s1, 0, 0, 0);
      s1 = __builtin_amdgcn_mfma_f32_16x16x32_bf16(qf1, k11, s1, 0, 0, 0);
    }
    if (j0 + 31 > q0w) {   // only tail tiles need the causal mask
#pragma unroll
      for (int r = 0; r < 4; ++r) {
        const int row = q0w + hi * 4 + r;
        if (j0 + lo > row)      s0[r] = -1e30f;
        if (j0 + 16 + lo > row) s1[r] = -1e30f;
      }
    }
    float al[4];
#pragma unroll
    for (int r = 0; r < 4; ++r) {
      float x = fmaxf(s0[r], s1[r]);
      x = fmaxf(x, __shfl_xor(x, 1, 16));
      x = fmaxf(x, __shfl_xor(x, 2, 16));
      x = fmaxf(x, __shfl_xor(x, 4, 16));
      x = fmaxf(x, __shfl_xor(x, 8, 16));
      const float mn = fmaxf(mrow[r], x);
      al[r] = __expf(mrow[r] - mn);       // first tile: exp(-huge) = 0
      mrow[r] = mn;
      const float p0 = __expf(s0[r] - mn);
      const float p1 = __expf(s1[r] - mn);
      s0[r] = p0; s1[r] = p1;
      float sm = p0 + p1;
      sm += __shfl_xor(sm, 1, 16);
      sm += __shfl_xor(sm, 2, 16);
      sm += __shfl_xor(sm, 4, 16);
      sm += __shfl_xor(sm, 8, 16);
      lrow[r] = lrow[r] * al[r] + sm;
    }
    // P -> bf16 A-fragment via per-wave LDS transpose (wave-internal DS order)
#pragma unroll
    for (int r = 0; r < 4; ++r) {
      pb[(hi * 4 + r) * 32 + lo]      = f2bf(s0[r]);
      pb[(hi * 4 + r) * 32 + 16 + lo] = f2bf(s1[r]);
    }
    const bf16x8 pf = *(const bf16x8*)(pb + lo * 32 + hi * 8);
#pragma unroll
    for (int n = 0; n < 4; ++n) {
#pragma unroll
      for (int r = 0; r < 4; ++r) o[n][r] *= al[r];
      const bf16x8 vf = *(const bf16x8*)(Vt + (size_t)(n * 16 + lo) * T_ + j0 + hi * 8);
      o[n] = __builtin_amdgcn_mfma_f32_16x16x32_bf16(pf, vf, o[n], 0, 0, 0);
    }
  }
#pragma unroll
  for (int n = 0; n < 4; ++n)
#pragma unroll
    for (int r = 0; r < 4; ++r) {
      const int t = q0w + hi * 4 + r;
      const float val = o[n][r] / lrow[r];
      yb[((size_t)(b * T_ + t)) * C_ + h * D_ + n * 16 + lo] = f2bf(val);
    }
}

extern "C" void kernel_launch(void* const* d_in, const int* in_sizes, int n_in,
                              void* d_out, int out_size, void* d_ws, size_t ws_size,
                              hipStream_t stream) {
  (void)in_sizes; (void)n_in; (void)out_size; (void)ws_size;
  const float* x    = (const float*)d_in[0];
  const float* rope = (const float*)d_in[1];
  const float* wqkv = (const float*)d_in[2];
  const float* wo   = (const float*)d_in[3];
  float* out = (float*)d_out;
  char* ws = (char*)d_ws;
  // workspace layout (bytes), total 92.8 MB
  u16* xb    = (u16*)(ws);              // 12582912  (8192x768 bf16) -- reused as yb
  u16* wqkvb = (u16*)(ws + 12582912);   //  3538944  (2304x768)
  u16* wob   = (u16*)(ws + 16121856);   //  1179648  (768x768)
  u16* qkvb  = (u16*)(ws + 17301504);   // 37748736  (8192x2304)
  u16* qb    = (u16*)(ws + 55050240);   // 12582912  (b,h,t,d)
  u16* kb    = (u16*)(ws + 67633152);   // 12582912  (b,h,t,d)
  u16* vtb   = (u16*)(ws + 80216064);   // 12582912  (b,h,d,t)
  u16* yb    = xb;                      // x is dead after QKV GEMM

  k_cvt<<<6144, 256, 0, stream>>>(x, xb);        // 6291456/1024
  k_cvt<<<1728, 256, 0, stream>>>(wqkv, wqkvb);  // 1769472/1024
  k_cvt<<<576,  256, 0, stream>>>(wo, wob);      //  589824/1024

  k_gemm_bt<0><<<dim3(18, 64), 256, 0, stream>>>(xb, wqkvb, qkvb, 8192, 2304, 768);
  k_rope<<<12288, 256, 0, stream>>>(qkvb, rope, qb, kb);
  k_vtrans<<<1536, 256, 0, stream>>>(qkvb, vtb);
  k_attn<<<dim3(32, 12, 4), 256, 0, stream>>>(qb, kb, vtb, yb);
  k_gemm_bt<1><<<dim3(6, 64), 256, 0, stream>>>(yb, wob, out, 8192, 768, 768);
}